// Round 11
// baseline (340.181 us; speedup 1.0000x reference)
//
#include <hip/hip_runtime.h>
#include <math.h>

using short8 = __attribute__((ext_vector_type(8))) short;
using f32x4 = __attribute__((ext_vector_type(4))) float;

// bf16 helpers
__device__ __forceinline__ float bflo(unsigned int u) {
  union { unsigned int i; float f; } v; v.i = u << 16; return v.f;
}
__device__ __forceinline__ float bfhi(unsigned int u) {
  union { unsigned int i; float f; } v; v.i = u & 0xFFFF0000u; return v.f;
}
__device__ __forceinline__ unsigned short f2bf1(float f) {  // RNE
  union { float f; unsigned int i; } v; v.f = f;
  return (unsigned short)((v.i + 0x7FFFu + ((v.i >> 16) & 1u)) >> 16);
}
__device__ __forceinline__ unsigned int f2bf_pack(float a, float b) {  // RNE
  union { float f; unsigned int i; } x, y; x.f = a; y.f = b;
  unsigned int xa = x.i + 0x7FFFu + ((x.i >> 16) & 1u);
  unsigned int yb = y.i + 0x7FFFu + ((y.i >> 16) & 1u);
  return (xa >> 16) | (yb & 0xFFFF0000u);
}

#define NBUCKET 196  // ceil(50000/256)

// ---------- prep0: zero ccnt/dhist + transpose/cast all 3 weights ----------
__global__ void prep0_kernel(const float* __restrict__ W0, const float* __restrict__ W1,
                             const float* __restrict__ W2, unsigned short* __restrict__ Wt0,
                             unsigned short* __restrict__ Wt1, unsigned short* __restrict__ Wt2,
                             int* __restrict__ ccnt, int* __restrict__ dhist) {
  int i = blockIdx.x * 256 + threadIdx.x;
  int gs = gridDim.x * 256;
  if (i < NBUCKET) ccnt[i] = 0;
  if (i < 1024) dhist[i] = 0;
  for (int j = i; j < 128 * 128; j += gs) {
    int c = j >> 7, k = j & 127;
    Wt0[c * 136 + k] = f2bf1(W0[(size_t)k * 128 + c]);
  }
  for (int j = i; j < 128 * 128; j += gs) {
    int c = j >> 7, k = j & 127;
    Wt1[c * 136 + k] = f2bf1(W1[(size_t)k * 128 + c]);
  }
  for (int j = i; j < 64 * 128; j += gs) {
    int c = j >> 7, k = j & 127;
    Wt2[c * 136 + k] = f2bf1(W2[(size_t)k * 64 + c]);
  }
}

// ---------- K2: coarse bucket count (dst>>8), LDS-aggregated ----------
__global__ __launch_bounds__(1024) void ccount_kernel(const int* __restrict__ ei, int E,
                                                      int N, int* __restrict__ ccnt) {
  __shared__ int lc[256];
  int t = threadIdx.x;
  if (t < 256) lc[t] = 0;
  __syncthreads();
  int e = blockIdx.x * 1024 + t;
  int etot = E + N;
  if (e < etot) {
    int d = (e < E) ? ei[E + e] : (e - E);
    atomicAdd(&lc[d >> 8], 1);
  }
  __syncthreads();
  if (t < NBUCKET) {
    int c = lc[t];
    if (c) atomicAdd(&ccnt[t], c);
  }
}

// ---------- K3: scan 196 coarse counts -> cbase, init gcursor ----------
__global__ void cscan_kernel(const int* __restrict__ ccnt, int* __restrict__ cbase,
                             int* __restrict__ gcursor, int etot) {
  __shared__ int sm[256];
  int t = threadIdx.x;
  int v = (t < NBUCKET) ? ccnt[t] : 0;
  sm[t] = v;
  __syncthreads();
#pragma unroll
  for (int off = 1; off < 256; off <<= 1) {
    int add = (t >= off) ? sm[t - off] : 0;
    __syncthreads();
    sm[t] += add;
    __syncthreads();
  }
  if (t < NBUCKET) {
    int ex = sm[t] - v;
    cbase[t] = ex;
    gcursor[t] = ex;
  }
  if (t == 0) cbase[NBUCKET] = etot;
}

// ---------- K4: bucket scatter with LDS presort (coalesced ebuf writes) -----
__global__ __launch_bounds__(1024) void bscatter_kernel(
    const int* __restrict__ ei, int E, int N, int* __restrict__ gcursor,
    uint2* __restrict__ ebuf) {
  __shared__ int cnt[256], excl[256], base[256];
  __shared__ uint2 buf[4096];
  const int t = threadIdx.x;
  const int etot = E + N;
  const int e0 = blockIdx.x * 4096;
  if (t < 256) cnt[t] = 0;
  __syncthreads();

  int sj[4], dj[4], rj[4], bj[4];
  bool vj[4];
#pragma unroll
  for (int j = 0; j < 4; ++j) {
    int e = e0 + j * 1024 + t;
    vj[j] = e < etot;
    if (vj[j]) {
      if (e < E) { sj[j] = ei[e]; dj[j] = ei[E + e]; }
      else       { sj[j] = e - E; dj[j] = e - E; }
      bj[j] = dj[j] >> 8;
      rj[j] = atomicAdd(&cnt[bj[j]], 1);
    }
  }
  __syncthreads();
  // exclusive scan of cnt -> excl (256 slots, first 256 threads)
  if (t < 256) excl[t] = cnt[t];
  __syncthreads();
#pragma unroll
  for (int off = 1; off < 256; off <<= 1) {
    int add = 0;
    if (t < 256 && t >= off) add = excl[t - off];
    __syncthreads();
    if (t < 256) excl[t] += add;
    __syncthreads();
  }
  // excl currently inclusive; convert: exclusive = inclusive - cnt
  if (t < 256) excl[t] -= cnt[t];
  __syncthreads();
  if (t < NBUCKET) {
    int c = cnt[t];
    base[t] = c ? atomicAdd(&gcursor[t], c) : 0;
  }
  __syncthreads();
  // presort into LDS
#pragma unroll
  for (int j = 0; j < 4; ++j)
    if (vj[j]) buf[excl[bj[j]] + rj[j]] = make_uint2((unsigned)sj[j], (unsigned)dj[j]);
  __syncthreads();
  // linear write-out (coalesced; consecutive slots -> consecutive global pos)
  int nv = etot - e0;
  if (nv > 4096) nv = 4096;
#pragma unroll
  for (int j = 0; j < 4; ++j) {
    int i = j * 1024 + t;
    if (i < nv) {
      uint2 u = buf[i];
      int b = (int)(u.y >> 8);
      ebuf[base[b] + (i - excl[b])] = u;
    }
  }
}

// ---------- K5: per-bucket CSR (rowptr + csr_src) + deghist fused ----------
__global__ __launch_bounds__(1024) void bcsr_kernel(
    const uint2* __restrict__ ebuf, const int* __restrict__ cbase,
    int* __restrict__ rowptr, int* __restrict__ csr_src, int* __restrict__ dhist,
    int N, int etot) {
  __shared__ int hist[256], hexcl[256];
  const int b = blockIdx.x;
  const int t = threadIdx.x;
  const int lo = cbase[b], hi = cbase[b + 1];
  const int node0 = b * 256;
  int nn = N - node0;
  if (nn > 256) nn = 256;
  if (t < 256) hist[t] = 0;
  __syncthreads();
  for (int i = lo + t; i < hi; i += 1024) {
    int ln = (int)(ebuf[i].y & 255u);
    atomicAdd(&hist[ln], 1);
  }
  __syncthreads();
  // deghist (real nodes only)
  if (t < nn) {
    int key = hist[t] < 1023 ? hist[t] : 1023;
    atomicAdd(&dhist[key], 1);
  }
  // exclusive scan hist -> hexcl
  if (t < 256) hexcl[t] = hist[t];
  __syncthreads();
#pragma unroll
  for (int off = 1; off < 256; off <<= 1) {
    int add = 0;
    if (t < 256 && t >= off) add = hexcl[t - off];
    __syncthreads();
    if (t < 256) hexcl[t] += add;
    __syncthreads();
  }
  if (t < 256) hexcl[t] -= hist[t];
  __syncthreads();
  if (t < nn) rowptr[node0 + t] = lo + hexcl[t];
  if (b == gridDim.x - 1 && t == 0) rowptr[N] = etot;
  // repurpose hist as rank cursor
  if (t < 256) hist[t] = hexcl[t];
  __syncthreads();
  for (int i = lo + t; i < hi; i += 1024) {
    uint2 u = ebuf[i];
    int ln = (int)(u.y & 255u);
    int r = atomicAdd(&hist[ln], 1);
    csr_src[lo + r] = (int)u.x;  // write inside block's contiguous window
  }
}

// ---------- K6: degree-histogram scan (1024 bins, 1 block x 256) ----------
__global__ void degscan_kernel(int* __restrict__ dhist) {
  __shared__ int arr[256];
  int t = threadIdx.x;
  int v0 = dhist[t * 4 + 0], v1 = dhist[t * 4 + 1];
  int v2 = dhist[t * 4 + 2], v3 = dhist[t * 4 + 3];
  int s0 = v0, s1 = s0 + v1, s2 = s1 + v2, s3 = s2 + v3;
  arr[t] = s3;
  __syncthreads();
#pragma unroll
  for (int off = 1; off < 256; off <<= 1) {
    int add = (t >= off) ? arr[t - off] : 0;
    __syncthreads();
    arr[t] += add;
    __syncthreads();
  }
  int base = (t > 0) ? arr[t - 1] : 0;
  dhist[t * 4 + 0] = base;
  dhist[t * 4 + 1] = base + s0;
  dhist[t * 4 + 2] = base + s1;
  dhist[t * 4 + 3] = base + s2;
}

// ---------- K7: degree counting-sort scatter (LDS-aggregated) ----------
__global__ void degscatter_kernel(const int* __restrict__ rowptr, int N,
                                  int* __restrict__ dhist, int* __restrict__ perm) {
  __shared__ int lc[1024];
  __shared__ int lb[1024];
  int t = threadIdx.x;
  for (int i = t; i < 1024; i += 256) lc[i] = 0;
  __syncthreads();
  int i = blockIdx.x * 256 + t;
  int key = 0, lr = 0;
  if (i < N) {
    int d = rowptr[i + 1] - rowptr[i];
    key = d < 1023 ? d : 1023;
    lr = atomicAdd(&lc[key], 1);
  }
  __syncthreads();
  for (int q = t; q < 1024; q += 256) {
    int c = lc[q];
    if (c) lb[q] = atomicAdd(&dhist[q], c);
  }
  __syncthreads();
  if (i < N) perm[lb[key] + lr] = i;
}

// ------------- MFMA GEMM: H(bf16) = X @ W, fused hl/hr epilogue --------------
template <int COLS, bool AF32>
__global__ __launch_bounds__(256) void gemm_mfma(
    const void* __restrict__ Xv, const unsigned short* __restrict__ Wt,
    const float* __restrict__ al, const float* __restrict__ ar,
    unsigned short* __restrict__ H, float* __restrict__ hl,
    float* __restrict__ hr, int N) {
  constexpr int NT = COLS / 16;
  __shared__ unsigned short Ws[COLS * 136];
  const int tid = threadIdx.x;
  {
    const unsigned int* wg = (const unsigned int*)Wt;
    unsigned int* ws = (unsigned int*)Ws;
    for (int i = tid; i < COLS * 68; i += 256) ws[i] = wg[i];
  }
  __syncthreads();

  const int w = tid >> 6, l = tid & 63;
  const int l15 = l & 15, lg = l >> 4;
  const int r0 = blockIdx.x * 64 + w * 16;

  f32x4 acc[NT];
#pragma unroll
  for (int t = 0; t < NT; ++t)
#pragma unroll
    for (int j = 0; j < 4; ++j) acc[t][j] = 0.f;

  int arow = r0 + l15;
  if (arow > N - 1) arow = N - 1;

#pragma unroll
  for (int ks = 0; ks < 4; ++ks) {
    short8 af;
    if constexpr (AF32) {
      const float* xp = (const float*)Xv + (size_t)arow * 128 + ks * 32 + lg * 8;
      float4 x0 = *(const float4*)xp;
      float4 x1 = *(const float4*)(xp + 4);
      af[0] = (short)f2bf1(x0.x); af[1] = (short)f2bf1(x0.y);
      af[2] = (short)f2bf1(x0.z); af[3] = (short)f2bf1(x0.w);
      af[4] = (short)f2bf1(x1.x); af[5] = (short)f2bf1(x1.y);
      af[6] = (short)f2bf1(x1.z); af[7] = (short)f2bf1(x1.w);
    } else {
      af = *(const short8*)((const unsigned short*)Xv + (size_t)arow * 128 + ks * 32 + lg * 8);
    }
#pragma unroll
    for (int t = 0; t < NT; ++t) {
      short8 bf = *(const short8*)(&Ws[(t * 16 + l15) * 136 + ks * 32 + lg * 8]);
      acc[t] = __builtin_amdgcn_mfma_f32_16x16x32_bf16(af, bf, acc[t], 0, 0, 0);
    }
  }

  const int orow = r0 + lg * 4;
  float pl4[4] = {0.f, 0.f, 0.f, 0.f}, pr4[4] = {0.f, 0.f, 0.f, 0.f};
#pragma unroll
  for (int t = 0; t < NT; ++t) {
    float av = al[t * 16 + l15], rv = ar[t * 16 + l15];
#pragma unroll
    for (int r = 0; r < 4; ++r) {
      pl4[r] = fmaf(acc[t][r], av, pl4[r]);
      pr4[r] = fmaf(acc[t][r], rv, pr4[r]);
    }
#pragma unroll
    for (int r = 0; r < 4; ++r) {
      int row = orow + r;
      if (row < N) H[(size_t)row * COLS + t * 16 + l15] = f2bf1(acc[t][r]);
    }
  }
#pragma unroll
  for (int off = 1; off < 16; off <<= 1) {
#pragma unroll
    for (int r = 0; r < 4; ++r) {
      pl4[r] += __shfl_xor(pl4[r], off);
      pr4[r] += __shfl_xor(pr4[r], off);
    }
  }
  if (l15 == 0) {
#pragma unroll
    for (int r = 0; r < 4; ++r) {
      int row = orow + r;
      if (row < N) { hl[row] = pl4[r]; hr[row] = pr4[r]; }
    }
  }
}

// ---------------- per-node attention + aggregation ----------------
// Wave = 4 groups x 16 lanes; each GROUP owns one node (quartile-strided).
// 2-edge-deep H pipeline + 4-deep index prefetch. Defer-max softmax (THR=30).
template <int COLS, bool LAST>
__global__ __launch_bounds__(256, 6) void node_kernel(
    const unsigned short* __restrict__ H, const float* __restrict__ hl,
    const float* __restrict__ hr, const int* __restrict__ rowptr,
    const int* __restrict__ csr_src, const int* __restrict__ perm,
    const float* __restrict__ b, void* __restrict__ OUTv, int N) {
  constexpr int GS = 16;
  constexpr int EPL = COLS / GS;  // 8 (COLS=128) or 4 (COLS=64)
  constexpr int NU = EPL / 2;     // uints per lane: 4 or 2
  const int lane = threadIdx.x & 63;
  const int g = lane >> 4, l = lane & 15;
  const int C = (N + 3) / 4;
  const int c = blockIdx.x * 4 + (threadIdx.x >> 6);
  const int idx = g * C + c;
  const bool active = (c < C) && (idx < N);
  const int node = active ? perm[idx] : 0;

  float hi[EPL];
  {
    unsigned int tmp[NU];
    const unsigned short* hp = H + (size_t)node * COLS + l * EPL;
    if constexpr (NU == 4) *(uint4*)tmp = *(const uint4*)hp;
    else                   *(uint2*)tmp = *(const uint2*)hp;
#pragma unroll
    for (int u = 0; u < NU; ++u) { hi[2 * u] = bflo(tmp[u]); hi[2 * u + 1] = bfhi(tmp[u]); }
  }
  const float hri = hr[node];
  const int start = active ? rowptr[node] : 0;
  const int end = active ? rowptr[node + 1] : 0;

  float m = -INFINITY, sumw = 0.f;
  float acc[EPL];
#pragma unroll
  for (int j = 0; j < EPL; ++j) acc[j] = 0.f;

  unsigned int hvA[NU], hvB[NU];
  float hlA = 0.f, hlB = 0.f;
  int e = start;
  if (e < end) {
    int s = csr_src[e];
    hlA = hl[s];
    const unsigned short* hp = H + (size_t)s * COLS + l * EPL;
    if constexpr (NU == 4) *(uint4*)hvA = *(const uint4*)hp;
    else                   *(uint2*)hvA = *(const uint2*)hp;
  }
  if (e + 1 < end) {
    int s = csr_src[e + 1];
    hlB = hl[s];
    const unsigned short* hp = H + (size_t)s * COLS + l * EPL;
    if constexpr (NU == 4) *(uint4*)hvB = *(const uint4*)hp;
    else                   *(uint2*)hvB = *(const uint2*)hp;
  }
  int i2 = (e + 2 < end) ? csr_src[e + 2] : 0;
  int i3 = (e + 3 < end) ? csr_src[e + 3] : 0;

  auto COMPUTE = [&](const float* ch, float chl) {
    float d = 0.f;
#pragma unroll
    for (int j = 0; j < EPL; ++j) d = fmaf(hi[j], ch[j], d);
    d += __shfl_xor(d, 1);
    d += __shfl_xor(d, 2);
    d += __shfl_xor(d, 4);
    d += __shfl_xor(d, 8);
    float gate = 1.f / (1.f + __expf(-d));
    float a = (chl + hri) * gate;
    a = (a >= 0.f) ? a : 0.2f * a;
    float dm = a - m;
    if (dm > 30.f) {  // first edge (m=-inf) or rare big jump
      float sc = __expf(-dm);
      sumw *= sc;
#pragma unroll
      for (int j = 0; j < EPL; ++j) acc[j] *= sc;
      m = a;
      dm = 0.f;
    }
    float w = __expf(dm);  // bounded by e^30 - f32 safe
    sumw += w;
#pragma unroll
    for (int j = 0; j < EPL; ++j) acc[j] = fmaf(w, ch[j], acc[j]);
  };

  while (e + 1 < end) {
    float chA[EPL], chB[EPL];
#pragma unroll
    for (int u = 0; u < NU; ++u) { chA[2 * u] = bflo(hvA[u]); chA[2 * u + 1] = bfhi(hvA[u]); }
    float clA = hlA;
    if (e + 2 < end) {
      hlA = hl[i2];
      const unsigned short* hp = H + (size_t)i2 * COLS + l * EPL;
      if constexpr (NU == 4) *(uint4*)hvA = *(const uint4*)hp;
      else                   *(uint2*)hvA = *(const uint2*)hp;
    }
#pragma unroll
    for (int u = 0; u < NU; ++u) { chB[2 * u] = bflo(hvB[u]); chB[2 * u + 1] = bfhi(hvB[u]); }
    float clB = hlB;
    if (e + 3 < end) {
      hlB = hl[i3];
      const unsigned short* hp = H + (size_t)i3 * COLS + l * EPL;
      if constexpr (NU == 4) *(uint4*)hvB = *(const uint4*)hp;
      else                   *(uint2*)hvB = *(const uint2*)hp;
    }
    i2 = (e + 4 < end) ? csr_src[e + 4] : 0;
    i3 = (e + 5 < end) ? csr_src[e + 5] : 0;
    COMPUTE(chA, clA);
    COMPUTE(chB, clB);
    e += 2;
  }
  if (e < end) {
    float chA[EPL];
#pragma unroll
    for (int u = 0; u < NU; ++u) { chA[2 * u] = bflo(hvA[u]); chA[2 * u + 1] = bfhi(hvA[u]); }
    COMPUTE(chA, hlA);
  }

  if (active) {
    const float inv = 1.f / (sumw + 1e-16f);
    float o[EPL];
    const float* bp = b + l * EPL;
#pragma unroll
    for (int j = 0; j < EPL; ++j) o[j] = fmaxf(acc[j] * inv + bp[j], 0.f);

    if constexpr (LAST) {
      float* OUT = (float*)OUTv;
      float mx = o[0];
#pragma unroll
      for (int j = 1; j < EPL; ++j) mx = fmaxf(mx, o[j]);
      mx = fmaxf(mx, __shfl_xor(mx, 1));
      mx = fmaxf(mx, __shfl_xor(mx, 2));
      mx = fmaxf(mx, __shfl_xor(mx, 4));
      mx = fmaxf(mx, __shfl_xor(mx, 8));
      float es = 0.f;
#pragma unroll
      for (int j = 0; j < EPL; ++j) es += __expf(o[j] - mx);
      es += __shfl_xor(es, 1);
      es += __shfl_xor(es, 2);
      es += __shfl_xor(es, 4);
      es += __shfl_xor(es, 8);
      float ls = logf(es);
      float4 ov = make_float4(o[0] - mx - ls, o[1] - mx - ls,
                              o[2] - mx - ls, o[3] - mx - ls);
      *(float4*)(&OUT[(size_t)node * 64 + l * 4]) = ov;
    } else {
      unsigned short* OUT = (unsigned short*)OUTv;
      unsigned int pk[NU];
#pragma unroll
      for (int u = 0; u < NU; ++u) pk[u] = f2bf_pack(o[2 * u], o[2 * u + 1]);
      *(uint4*)(OUT + (size_t)node * COLS + l * EPL) =
          make_uint4(pk[0], pk[1], pk[2], pk[3]);
    }
  }
}

// ---------------- launch ----------------
extern "C" void kernel_launch(void* const* d_in, const int* in_sizes, int n_in,
                              void* d_out, int out_size, void* d_ws, size_t ws_size,
                              hipStream_t stream) {
  const float* x = (const float*)d_in[0];
  const int* ei = (const int*)d_in[1];
  const float* W0 = (const float*)d_in[2];
  const float* al0 = (const float*)d_in[3];
  const float* ar0 = (const float*)d_in[4];
  const float* b0 = (const float*)d_in[5];
  const float* W1 = (const float*)d_in[6];
  const float* al1 = (const float*)d_in[7];
  const float* ar1 = (const float*)d_in[8];
  const float* b1 = (const float*)d_in[9];
  const float* W2 = (const float*)d_in[10];
  const float* al2 = (const float*)d_in[11];
  const float* ar2 = (const float*)d_in[12];
  const float* b2 = (const float*)d_in[13];

  const int N = in_sizes[0] / 128;  // 50000
  const int E = in_sizes[1] / 2;    // 640000
  const int ETOT = E + N;

  char* p = (char*)d_ws;
  auto carve = [&](size_t bytes) {
    void* r = (void*)p;
    p += (bytes + 255) & ~(size_t)255;
    return r;
  };
  unsigned short* Hb = (unsigned short*)carve((size_t)N * 128 * 2);
  unsigned short* Ob = (unsigned short*)carve((size_t)N * 128 * 2);
  float* hl = (float*)carve((size_t)N * sizeof(float));
  float* hr = (float*)carve((size_t)N * sizeof(float));
  int* ccnt = (int*)carve(256 * sizeof(int));
  int* cbase = (int*)carve(256 * sizeof(int));
  int* gcursor = (int*)carve(256 * sizeof(int));
  uint2* ebuf = (uint2*)carve((size_t)ETOT * sizeof(uint2));
  int* rowptr = (int*)carve((size_t)(N + 1) * sizeof(int));
  int* csr_src = (int*)carve((size_t)ETOT * sizeof(int));
  int* dhist = (int*)carve(1024 * sizeof(int));
  int* perm = (int*)carve((size_t)N * sizeof(int));
  unsigned short* Wt0 = (unsigned short*)carve(128 * 136 * 2);
  unsigned short* Wt1 = (unsigned short*)carve(128 * 136 * 2);
  unsigned short* Wt2 = (unsigned short*)carve(64 * 136 * 2);

  const int nbs = (N + 255) / 256;  // 196 = NBUCKET

  // ---- CSR build (bucketed, line-dense writes) ----
  prep0_kernel<<<nbs, 256, 0, stream>>>(W0, W1, W2, Wt0, Wt1, Wt2, ccnt, dhist);
  ccount_kernel<<<(ETOT + 1023) / 1024, 1024, 0, stream>>>(ei, E, N, ccnt);
  cscan_kernel<<<1, 256, 0, stream>>>(ccnt, cbase, gcursor, ETOT);
  bscatter_kernel<<<(ETOT + 4095) / 4096, 1024, 0, stream>>>(ei, E, N, gcursor, ebuf);
  bcsr_kernel<<<NBUCKET, 1024, 0, stream>>>(ebuf, cbase, rowptr, csr_src, dhist, N, ETOT);
  degscan_kernel<<<1, 256, 0, stream>>>(dhist);
  degscatter_kernel<<<nbs, 256, 0, stream>>>(rowptr, N, dhist, perm);

  const int gemm_grid = (N + 63) / 64;
  const int C = (N + 3) / 4;
  const int node_grid = (C + 3) / 4;

  // layer 0: A = x (f32, cast in-flight)
  gemm_mfma<128, true><<<gemm_grid, 256, 0, stream>>>(x, Wt0, al0, ar0, Hb, hl, hr, N);
  node_kernel<128, false><<<node_grid, 256, 0, stream>>>(Hb, hl, hr, rowptr, csr_src, perm, b0, Ob, N);

  // layer 1: A = Ob (bf16)
  gemm_mfma<128, false><<<gemm_grid, 256, 0, stream>>>(Ob, Wt1, al1, ar1, Hb, hl, hr, N);
  node_kernel<128, false><<<node_grid, 256, 0, stream>>>(Hb, hl, hr, rowptr, csr_src, perm, b1, Ob, N);

  // layer 2: A = Ob (bf16), COLS = 64
  gemm_mfma<64, false><<<gemm_grid, 256, 0, stream>>>(Ob, Wt2, al2, ar2, Hb, hl, hr, N);
  node_kernel<64, true><<<node_grid, 256, 0, stream>>>(Hb, hl, hr, rowptr, csr_src, perm, b2,
                                                       d_out, N);
}

// Round 12
// 195.061 us; speedup vs baseline: 1.7440x; 1.7440x over previous
//
#include <hip/hip_runtime.h>
#include <math.h>

using short8 = __attribute__((ext_vector_type(8))) short;
using f32x4 = __attribute__((ext_vector_type(4))) float;

// bf16 helpers
__device__ __forceinline__ float bflo(unsigned int u) {
  union { unsigned int i; float f; } v; v.i = u << 16; return v.f;
}
__device__ __forceinline__ float bfhi(unsigned int u) {
  union { unsigned int i; float f; } v; v.i = u & 0xFFFF0000u; return v.f;
}
__device__ __forceinline__ unsigned short f2bf1(float f) {  // RNE
  union { float f; unsigned int i; } v; v.f = f;
  return (unsigned short)((v.i + 0x7FFFu + ((v.i >> 16) & 1u)) >> 16);
}
__device__ __forceinline__ unsigned int f2bf_pack(float a, float b) {  // RNE
  union { float f; unsigned int i; } x, y; x.f = a; y.f = b;
  unsigned int xa = x.i + 0x7FFFu + ((x.i >> 16) & 1u);
  unsigned int yb = y.i + 0x7FFFu + ((y.i >> 16) & 1u);
  return (xa >> 16) | (yb & 0xFFFF0000u);
}

#define NBUCKET 196  // ceil(50000/256)

// ---------- prep0: zero ccnt/dhist + transpose/cast all 3 weights ----------
__global__ void prep0_kernel(const float* __restrict__ W0, const float* __restrict__ W1,
                             const float* __restrict__ W2, unsigned short* __restrict__ Wt0,
                             unsigned short* __restrict__ Wt1, unsigned short* __restrict__ Wt2,
                             int* __restrict__ ccnt, int* __restrict__ dhist) {
  int i = blockIdx.x * 256 + threadIdx.x;
  int gs = gridDim.x * 256;
  if (i < NBUCKET) ccnt[i] = 0;
  if (i < 1024) dhist[i] = 0;
  for (int j = i; j < 128 * 128; j += gs) {
    int c = j >> 7, k = j & 127;
    Wt0[c * 136 + k] = f2bf1(W0[(size_t)k * 128 + c]);
  }
  for (int j = i; j < 128 * 128; j += gs) {
    int c = j >> 7, k = j & 127;
    Wt1[c * 136 + k] = f2bf1(W1[(size_t)k * 128 + c]);
  }
  for (int j = i; j < 64 * 128; j += gs) {
    int c = j >> 7, k = j & 127;
    Wt2[c * 136 + k] = f2bf1(W2[(size_t)k * 64 + c]);
  }
}

// ---------- K2: coarse bucket count (dst>>8), LDS-aggregated ----------
__global__ __launch_bounds__(1024) void ccount_kernel(const int* __restrict__ ei, int E,
                                                      int N, int* __restrict__ ccnt) {
  __shared__ int lc[256];
  int t = threadIdx.x;
  if (t < 256) lc[t] = 0;
  __syncthreads();
  int e = blockIdx.x * 1024 + t;
  int etot = E + N;
  if (e < etot) {
    int d = (e < E) ? ei[E + e] : (e - E);
    atomicAdd(&lc[d >> 8], 1);
  }
  __syncthreads();
  if (t < NBUCKET) {
    int c = lc[t];
    if (c) atomicAdd(&ccnt[t], c);
  }
}

// ---------- K3: scan 196 coarse counts -> cbase, init gcursor ----------
__global__ void cscan_kernel(const int* __restrict__ ccnt, int* __restrict__ cbase,
                             int* __restrict__ gcursor, int etot) {
  __shared__ int sm[256];
  int t = threadIdx.x;
  int v = (t < NBUCKET) ? ccnt[t] : 0;
  sm[t] = v;
  __syncthreads();
#pragma unroll
  for (int off = 1; off < 256; off <<= 1) {
    int add = (t >= off) ? sm[t - off] : 0;
    __syncthreads();
    sm[t] += add;
    __syncthreads();
  }
  if (t < NBUCKET) {
    int ex = sm[t] - v;
    cbase[t] = ex;
    gcursor[t] = ex;
  }
  if (t == 0) cbase[NBUCKET] = etot;
}

// ---------- K4: bucket scatter with LDS presort (coalesced ebuf writes) -----
__global__ __launch_bounds__(1024) void bscatter_kernel(
    const int* __restrict__ ei, int E, int N, int* __restrict__ gcursor,
    uint2* __restrict__ ebuf) {
  __shared__ int cnt[256], excl[256], base[256];
  __shared__ uint2 buf[4096];
  const int t = threadIdx.x;
  const int etot = E + N;
  const int e0 = blockIdx.x * 4096;
  if (t < 256) cnt[t] = 0;
  __syncthreads();

  int sj[4], dj[4], rj[4], bj[4];
  bool vj[4];
#pragma unroll
  for (int j = 0; j < 4; ++j) {
    int e = e0 + j * 1024 + t;
    vj[j] = e < etot;
    if (vj[j]) {
      if (e < E) { sj[j] = ei[e]; dj[j] = ei[E + e]; }
      else       { sj[j] = e - E; dj[j] = e - E; }
      bj[j] = dj[j] >> 8;
      rj[j] = atomicAdd(&cnt[bj[j]], 1);
    }
  }
  __syncthreads();
  // exclusive scan of cnt -> excl
  if (t < 256) excl[t] = cnt[t];
  __syncthreads();
#pragma unroll
  for (int off = 1; off < 256; off <<= 1) {
    int add = 0;
    if (t < 256 && t >= off) add = excl[t - off];
    __syncthreads();
    if (t < 256) excl[t] += add;
    __syncthreads();
  }
  if (t < 256) excl[t] -= cnt[t];
  __syncthreads();
  if (t < NBUCKET) {
    int c = cnt[t];
    base[t] = c ? atomicAdd(&gcursor[t], c) : 0;
  }
  __syncthreads();
  // presort into LDS
#pragma unroll
  for (int j = 0; j < 4; ++j)
    if (vj[j]) buf[excl[bj[j]] + rj[j]] = make_uint2((unsigned)sj[j], (unsigned)dj[j]);
  __syncthreads();
  // linear write-out (coalesced)
  int nv = etot - e0;
  if (nv > 4096) nv = 4096;
#pragma unroll
  for (int j = 0; j < 4; ++j) {
    int i = j * 1024 + t;
    if (i < nv) {
      uint2 u = buf[i];
      int b = (int)(u.y >> 8);
      ebuf[base[b] + (i - excl[b])] = u;
    }
  }
}

// ---------- K5: per-bucket CSR (rowptr + csr_src) + deghist (LDS-agg) -------
__global__ __launch_bounds__(1024) void bcsr_kernel(
    const uint2* __restrict__ ebuf, const int* __restrict__ cbase,
    int* __restrict__ rowptr, int* __restrict__ csr_src, int* __restrict__ dhist,
    int N, int etot) {
  __shared__ int hist[256], hexcl[256];
  __shared__ int lh[1024];  // LDS-aggregated degree histogram
  const int b = blockIdx.x;
  const int t = threadIdx.x;
  const int lo = cbase[b], hi = cbase[b + 1];
  const int node0 = b * 256;
  int nn = N - node0;
  if (nn > 256) nn = 256;
  if (t < 256) hist[t] = 0;
  if (t < 1024) lh[t] = 0;
  __syncthreads();
  for (int i = lo + t; i < hi; i += 1024) {
    int ln = (int)(ebuf[i].y & 255u);
    atomicAdd(&hist[ln], 1);
  }
  __syncthreads();
  // deghist: aggregate in LDS, then <=#distinct-degree global adds per block
  if (t < nn) {
    int key = hist[t] < 1023 ? hist[t] : 1023;
    atomicAdd(&lh[key], 1);
  }
  // exclusive scan hist -> hexcl
  if (t < 256) hexcl[t] = hist[t];
  __syncthreads();
#pragma unroll
  for (int off = 1; off < 256; off <<= 1) {
    int add = 0;
    if (t < 256 && t >= off) add = hexcl[t - off];
    __syncthreads();
    if (t < 256) hexcl[t] += add;
    __syncthreads();
  }
  if (t < 256) hexcl[t] -= hist[t];
  __syncthreads();
  if (t < nn) rowptr[node0 + t] = lo + hexcl[t];
  if (b == gridDim.x - 1 && t == 0) rowptr[N] = etot;
  // flush LDS degree histogram to global (few distinct bins -> few atomics)
  if (t < 1024) {
    int c = lh[t];
    if (c) atomicAdd(&dhist[t], c);
  }
  // repurpose hist as rank cursor
  if (t < 256) hist[t] = hexcl[t];
  __syncthreads();
  for (int i = lo + t; i < hi; i += 1024) {
    uint2 u = ebuf[i];
    int ln = (int)(u.y & 255u);
    int r = atomicAdd(&hist[ln], 1);
    csr_src[lo + r] = (int)u.x;  // write inside block's contiguous window
  }
}

// ---------- K6: degree-histogram scan (1024 bins, 1 block x 256) ----------
__global__ void degscan_kernel(int* __restrict__ dhist) {
  __shared__ int arr[256];
  int t = threadIdx.x;
  int v0 = dhist[t * 4 + 0], v1 = dhist[t * 4 + 1];
  int v2 = dhist[t * 4 + 2], v3 = dhist[t * 4 + 3];
  int s0 = v0, s1 = s0 + v1, s2 = s1 + v2, s3 = s2 + v3;
  arr[t] = s3;
  __syncthreads();
#pragma unroll
  for (int off = 1; off < 256; off <<= 1) {
    int add = (t >= off) ? arr[t - off] : 0;
    __syncthreads();
    arr[t] += add;
    __syncthreads();
  }
  int base = (t > 0) ? arr[t - 1] : 0;
  dhist[t * 4 + 0] = base;
  dhist[t * 4 + 1] = base + s0;
  dhist[t * 4 + 2] = base + s1;
  dhist[t * 4 + 3] = base + s2;
}

// ---------- K7: degree counting-sort scatter (LDS-aggregated) ----------
__global__ void degscatter_kernel(const int* __restrict__ rowptr, int N,
                                  int* __restrict__ dhist, int* __restrict__ perm) {
  __shared__ int lc[1024];
  __shared__ int lb[1024];
  int t = threadIdx.x;
  for (int i = t; i < 1024; i += 256) lc[i] = 0;
  __syncthreads();
  int i = blockIdx.x * 256 + t;
  int key = 0, lr = 0;
  if (i < N) {
    int d = rowptr[i + 1] - rowptr[i];
    key = d < 1023 ? d : 1023;
    lr = atomicAdd(&lc[key], 1);
  }
  __syncthreads();
  for (int q = t; q < 1024; q += 256) {
    int c = lc[q];
    if (c) lb[q] = atomicAdd(&dhist[q], c);
  }
  __syncthreads();
  if (i < N) perm[lb[key] + lr] = i;
}

// ------------- MFMA GEMM: H(bf16) = X @ W, fused hl/hr epilogue --------------
template <int COLS, bool AF32>
__global__ __launch_bounds__(256) void gemm_mfma(
    const void* __restrict__ Xv, const unsigned short* __restrict__ Wt,
    const float* __restrict__ al, const float* __restrict__ ar,
    unsigned short* __restrict__ H, float* __restrict__ hl,
    float* __restrict__ hr, int N) {
  constexpr int NT = COLS / 16;
  __shared__ unsigned short Ws[COLS * 136];
  const int tid = threadIdx.x;
  {
    const unsigned int* wg = (const unsigned int*)Wt;
    unsigned int* ws = (unsigned int*)Ws;
    for (int i = tid; i < COLS * 68; i += 256) ws[i] = wg[i];
  }
  __syncthreads();

  const int w = tid >> 6, l = tid & 63;
  const int l15 = l & 15, lg = l >> 4;
  const int r0 = blockIdx.x * 64 + w * 16;

  f32x4 acc[NT];
#pragma unroll
  for (int t = 0; t < NT; ++t)
#pragma unroll
    for (int j = 0; j < 4; ++j) acc[t][j] = 0.f;

  int arow = r0 + l15;
  if (arow > N - 1) arow = N - 1;

#pragma unroll
  for (int ks = 0; ks < 4; ++ks) {
    short8 af;
    if constexpr (AF32) {
      const float* xp = (const float*)Xv + (size_t)arow * 128 + ks * 32 + lg * 8;
      float4 x0 = *(const float4*)xp;
      float4 x1 = *(const float4*)(xp + 4);
      af[0] = (short)f2bf1(x0.x); af[1] = (short)f2bf1(x0.y);
      af[2] = (short)f2bf1(x0.z); af[3] = (short)f2bf1(x0.w);
      af[4] = (short)f2bf1(x1.x); af[5] = (short)f2bf1(x1.y);
      af[6] = (short)f2bf1(x1.z); af[7] = (short)f2bf1(x1.w);
    } else {
      af = *(const short8*)((const unsigned short*)Xv + (size_t)arow * 128 + ks * 32 + lg * 8);
    }
#pragma unroll
    for (int t = 0; t < NT; ++t) {
      short8 bf = *(const short8*)(&Ws[(t * 16 + l15) * 136 + ks * 32 + lg * 8]);
      acc[t] = __builtin_amdgcn_mfma_f32_16x16x32_bf16(af, bf, acc[t], 0, 0, 0);
    }
  }

  const int orow = r0 + lg * 4;
  float pl4[4] = {0.f, 0.f, 0.f, 0.f}, pr4[4] = {0.f, 0.f, 0.f, 0.f};
#pragma unroll
  for (int t = 0; t < NT; ++t) {
    float av = al[t * 16 + l15], rv = ar[t * 16 + l15];
#pragma unroll
    for (int r = 0; r < 4; ++r) {
      pl4[r] = fmaf(acc[t][r], av, pl4[r]);
      pr4[r] = fmaf(acc[t][r], rv, pr4[r]);
    }
#pragma unroll
    for (int r = 0; r < 4; ++r) {
      int row = orow + r;
      if (row < N) H[(size_t)row * COLS + t * 16 + l15] = f2bf1(acc[t][r]);
    }
  }
#pragma unroll
  for (int off = 1; off < 16; off <<= 1) {
#pragma unroll
    for (int r = 0; r < 4; ++r) {
      pl4[r] += __shfl_xor(pl4[r], off);
      pr4[r] += __shfl_xor(pr4[r], off);
    }
  }
  if (l15 == 0) {
#pragma unroll
    for (int r = 0; r < 4; ++r) {
      int row = orow + r;
      if (row < N) { hl[row] = pl4[r]; hr[row] = pr4[r]; }
    }
  }
}

// ---------------- per-node attention + aggregation ----------------
// Wave = 4 groups x 16 lanes; each GROUP owns one node (quartile-strided).
// 2-edge-deep H pipeline + 4-deep index prefetch. Defer-max softmax (THR=30).
template <int COLS, bool LAST>
__global__ __launch_bounds__(256, 6) void node_kernel(
    const unsigned short* __restrict__ H, const float* __restrict__ hl,
    const float* __restrict__ hr, const int* __restrict__ rowptr,
    const int* __restrict__ csr_src, const int* __restrict__ perm,
    const float* __restrict__ b, void* __restrict__ OUTv, int N) {
  constexpr int GS = 16;
  constexpr int EPL = COLS / GS;  // 8 (COLS=128) or 4 (COLS=64)
  constexpr int NU = EPL / 2;     // uints per lane: 4 or 2
  const int lane = threadIdx.x & 63;
  const int g = lane >> 4, l = lane & 15;
  const int C = (N + 3) / 4;
  const int c = blockIdx.x * 4 + (threadIdx.x >> 6);
  const int idx = g * C + c;
  const bool active = (c < C) && (idx < N);
  const int node = active ? perm[idx] : 0;

  float hi[EPL];
  {
    unsigned int tmp[NU];
    const unsigned short* hp = H + (size_t)node * COLS + l * EPL;
    if constexpr (NU == 4) *(uint4*)tmp = *(const uint4*)hp;
    else                   *(uint2*)tmp = *(const uint2*)hp;
#pragma unroll
    for (int u = 0; u < NU; ++u) { hi[2 * u] = bflo(tmp[u]); hi[2 * u + 1] = bfhi(tmp[u]); }
  }
  const float hri = hr[node];
  const int start = active ? rowptr[node] : 0;
  const int end = active ? rowptr[node + 1] : 0;

  float m = -INFINITY, sumw = 0.f;
  float acc[EPL];
#pragma unroll
  for (int j = 0; j < EPL; ++j) acc[j] = 0.f;

  unsigned int hvA[NU], hvB[NU];
  float hlA = 0.f, hlB = 0.f;
  int e = start;
  if (e < end) {
    int s = csr_src[e];
    hlA = hl[s];
    const unsigned short* hp = H + (size_t)s * COLS + l * EPL;
    if constexpr (NU == 4) *(uint4*)hvA = *(const uint4*)hp;
    else                   *(uint2*)hvA = *(const uint2*)hp;
  }
  if (e + 1 < end) {
    int s = csr_src[e + 1];
    hlB = hl[s];
    const unsigned short* hp = H + (size_t)s * COLS + l * EPL;
    if constexpr (NU == 4) *(uint4*)hvB = *(const uint4*)hp;
    else                   *(uint2*)hvB = *(const uint2*)hp;
  }
  int i2 = (e + 2 < end) ? csr_src[e + 2] : 0;
  int i3 = (e + 3 < end) ? csr_src[e + 3] : 0;

  auto COMPUTE = [&](const float* ch, float chl) {
    float d = 0.f;
#pragma unroll
    for (int j = 0; j < EPL; ++j) d = fmaf(hi[j], ch[j], d);
    d += __shfl_xor(d, 1);
    d += __shfl_xor(d, 2);
    d += __shfl_xor(d, 4);
    d += __shfl_xor(d, 8);
    float gate = 1.f / (1.f + __expf(-d));
    float a = (chl + hri) * gate;
    a = (a >= 0.f) ? a : 0.2f * a;
    float dm = a - m;
    if (dm > 30.f) {  // first edge (m=-inf) or rare big jump
      float sc = __expf(-dm);
      sumw *= sc;
#pragma unroll
      for (int j = 0; j < EPL; ++j) acc[j] *= sc;
      m = a;
      dm = 0.f;
    }
    float w = __expf(dm);  // bounded by e^30 - f32 safe
    sumw += w;
#pragma unroll
    for (int j = 0; j < EPL; ++j) acc[j] = fmaf(w, ch[j], acc[j]);
  };

  while (e + 1 < end) {
    float chA[EPL], chB[EPL];
#pragma unroll
    for (int u = 0; u < NU; ++u) { chA[2 * u] = bflo(hvA[u]); chA[2 * u + 1] = bfhi(hvA[u]); }
    float clA = hlA;
    if (e + 2 < end) {
      hlA = hl[i2];
      const unsigned short* hp = H + (size_t)i2 * COLS + l * EPL;
      if constexpr (NU == 4) *(uint4*)hvA = *(const uint4*)hp;
      else                   *(uint2*)hvA = *(const uint2*)hp;
    }
#pragma unroll
    for (int u = 0; u < NU; ++u) { chB[2 * u] = bflo(hvB[u]); chB[2 * u + 1] = bfhi(hvB[u]); }
    float clB = hlB;
    if (e + 3 < end) {
      hlB = hl[i3];
      const unsigned short* hp = H + (size_t)i3 * COLS + l * EPL;
      if constexpr (NU == 4) *(uint4*)hvB = *(const uint4*)hp;
      else                   *(uint2*)hvB = *(const uint2*)hp;
    }
    i2 = (e + 4 < end) ? csr_src[e + 4] : 0;
    i3 = (e + 5 < end) ? csr_src[e + 5] : 0;
    COMPUTE(chA, clA);
    COMPUTE(chB, clB);
    e += 2;
  }
  if (e < end) {
    float chA[EPL];
#pragma unroll
    for (int u = 0; u < NU; ++u) { chA[2 * u] = bflo(hvA[u]); chA[2 * u + 1] = bfhi(hvA[u]); }
    COMPUTE(chA, hlA);
  }

  if (active) {
    const float inv = 1.f / (sumw + 1e-16f);
    float o[EPL];
    const float* bp = b + l * EPL;
#pragma unroll
    for (int j = 0; j < EPL; ++j) o[j] = fmaxf(acc[j] * inv + bp[j], 0.f);

    if constexpr (LAST) {
      float* OUT = (float*)OUTv;
      float mx = o[0];
#pragma unroll
      for (int j = 1; j < EPL; ++j) mx = fmaxf(mx, o[j]);
      mx = fmaxf(mx, __shfl_xor(mx, 1));
      mx = fmaxf(mx, __shfl_xor(mx, 2));
      mx = fmaxf(mx, __shfl_xor(mx, 4));
      mx = fmaxf(mx, __shfl_xor(mx, 8));
      float es = 0.f;
#pragma unroll
      for (int j = 0; j < EPL; ++j) es += __expf(o[j] - mx);
      es += __shfl_xor(es, 1);
      es += __shfl_xor(es, 2);
      es += __shfl_xor(es, 4);
      es += __shfl_xor(es, 8);
      float ls = logf(es);
      float4 ov = make_float4(o[0] - mx - ls, o[1] - mx - ls,
                              o[2] - mx - ls, o[3] - mx - ls);
      *(float4*)(&OUT[(size_t)node * 64 + l * 4]) = ov;
    } else {
      unsigned short* OUT = (unsigned short*)OUTv;
      unsigned int pk[NU];
#pragma unroll
      for (int u = 0; u < NU; ++u) pk[u] = f2bf_pack(o[2 * u], o[2 * u + 1]);
      *(uint4*)(OUT + (size_t)node * COLS + l * EPL) =
          make_uint4(pk[0], pk[1], pk[2], pk[3]);
    }
  }
}

// ---------------- launch ----------------
extern "C" void kernel_launch(void* const* d_in, const int* in_sizes, int n_in,
                              void* d_out, int out_size, void* d_ws, size_t ws_size,
                              hipStream_t stream) {
  const float* x = (const float*)d_in[0];
  const int* ei = (const int*)d_in[1];
  const float* W0 = (const float*)d_in[2];
  const float* al0 = (const float*)d_in[3];
  const float* ar0 = (const float*)d_in[4];
  const float* b0 = (const float*)d_in[5];
  const float* W1 = (const float*)d_in[6];
  const float* al1 = (const float*)d_in[7];
  const float* ar1 = (const float*)d_in[8];
  const float* b1 = (const float*)d_in[9];
  const float* W2 = (const float*)d_in[10];
  const float* al2 = (const float*)d_in[11];
  const float* ar2 = (const float*)d_in[12];
  const float* b2 = (const float*)d_in[13];

  const int N = in_sizes[0] / 128;  // 50000
  const int E = in_sizes[1] / 2;    // 640000
  const int ETOT = E + N;

  char* p = (char*)d_ws;
  auto carve = [&](size_t bytes) {
    void* r = (void*)p;
    p += (bytes + 255) & ~(size_t)255;
    return r;
  };
  unsigned short* Hb = (unsigned short*)carve((size_t)N * 128 * 2);
  unsigned short* Ob = (unsigned short*)carve((size_t)N * 128 * 2);
  float* hl = (float*)carve((size_t)N * sizeof(float));
  float* hr = (float*)carve((size_t)N * sizeof(float));
  int* ccnt = (int*)carve(256 * sizeof(int));
  int* cbase = (int*)carve(256 * sizeof(int));
  int* gcursor = (int*)carve(256 * sizeof(int));
  uint2* ebuf = (uint2*)carve((size_t)ETOT * sizeof(uint2));
  int* rowptr = (int*)carve((size_t)(N + 1) * sizeof(int));
  int* csr_src = (int*)carve((size_t)ETOT * sizeof(int));
  int* dhist = (int*)carve(1024 * sizeof(int));
  int* perm = (int*)carve((size_t)N * sizeof(int));
  unsigned short* Wt0 = (unsigned short*)carve(128 * 136 * 2);
  unsigned short* Wt1 = (unsigned short*)carve(128 * 136 * 2);
  unsigned short* Wt2 = (unsigned short*)carve(64 * 136 * 2);

  const int nbs = (N + 255) / 256;  // 196 = NBUCKET

  // ---- CSR build (bucketed, line-dense writes) ----
  prep0_kernel<<<nbs, 256, 0, stream>>>(W0, W1, W2, Wt0, Wt1, Wt2, ccnt, dhist);
  ccount_kernel<<<(ETOT + 1023) / 1024, 1024, 0, stream>>>(ei, E, N, ccnt);
  cscan_kernel<<<1, 256, 0, stream>>>(ccnt, cbase, gcursor, ETOT);
  bscatter_kernel<<<(ETOT + 4095) / 4096, 1024, 0, stream>>>(ei, E, N, gcursor, ebuf);
  bcsr_kernel<<<NBUCKET, 1024, 0, stream>>>(ebuf, cbase, rowptr, csr_src, dhist, N, ETOT);
  degscan_kernel<<<1, 256, 0, stream>>>(dhist);
  degscatter_kernel<<<nbs, 256, 0, stream>>>(rowptr, N, dhist, perm);

  const int gemm_grid = (N + 63) / 64;
  const int C = (N + 3) / 4;
  const int node_grid = (C + 3) / 4;

  // layer 0: A = x (f32, cast in-flight)
  gemm_mfma<128, true><<<gemm_grid, 256, 0, stream>>>(x, Wt0, al0, ar0, Hb, hl, hr, N);
  node_kernel<128, false><<<node_grid, 256, 0, stream>>>(Hb, hl, hr, rowptr, csr_src, perm, b0, Ob, N);

  // layer 1: A = Ob (bf16)
  gemm_mfma<128, false><<<gemm_grid, 256, 0, stream>>>(Ob, Wt1, al1, ar1, Hb, hl, hr, N);
  node_kernel<128, false><<<node_grid, 256, 0, stream>>>(Hb, hl, hr, rowptr, csr_src, perm, b1, Ob, N);

  // layer 2: A = Ob (bf16), COLS = 64
  gemm_mfma<64, false><<<gemm_grid, 256, 0, stream>>>(Ob, Wt2, al2, ar2, Hb, hl, hr, N);
  node_kernel<64, true><<<node_grid, 256, 0, stream>>>(Hb, hl, hr, rowptr, csr_src, perm, b2,
                                                       d_out, N);
}